// Round 9
// baseline (135.093 us; speedup 1.0000x reference)
//
#include <hip/hip_runtime.h>
#include <hip/hip_bf16.h>

typedef __bf16 bf16x8 __attribute__((ext_vector_type(8)));
typedef float f32x4 __attribute__((ext_vector_type(4)));

#define DIM 128
#define LOG_2PI 1.8378770664093453f
#define NS_ITERS 4   // even (X ends in B2); e0^(2^4) ~ 3e-4 < bf16 floor w/ Rayleigh x0

__device__ __forceinline__ unsigned short f2bf(float f) {
    unsigned int u = __float_as_uint(f);
    u += 0x7FFFu + ((u >> 16) & 1u);
    return (unsigned short)(u >> 16);
}
__device__ __forceinline__ float bfu(unsigned short u) {
    return __uint_as_float((unsigned int)u << 16);
}
// fragment-order index: FO[(r>>3)*1024 + c*8 + (r&7)] = M[r][c]
__device__ __forceinline__ int foidx(int r, int c) {
    return ((r >> 3) << 10) + (c << 3) + (r & 7);
}

// acc += P^T * Q  (P,Q bf16 fragment order; conflict-free ds_read_b128)
__device__ __forceinline__ void mm_acc(const unsigned short* __restrict__ Ps,
                                       const unsigned short* __restrict__ Qs,
                                       f32x4* acc, int tr, int tcb, int l15, int l4)
{
#pragma unroll
    for (int kk = 0; kk < 4; ++kk) {
        const int kc = kk * 4 + l4;
        const bf16x8 a = *reinterpret_cast<const bf16x8*>(Ps + (kc << 10) + ((tr * 16 + l15) << 3));
#pragma unroll
        for (int c = 0; c < 4; ++c) {
            const bf16x8 b = *reinterpret_cast<const bf16x8*>(Qs + (kc << 10) + (((tcb + c) * 16 + l15) << 3));
            acc[c] = __builtin_amdgcn_mfma_f32_16x16x32_bf16(a, b, acc[c], 0, 0, 0);
        }
    }
}

// packed writeback: rows r0..r0+3 are 4 contiguous 8-aligned shorts -> b64 store
__device__ __forceinline__ void wb_vec(unsigned short* __restrict__ C, const f32x4* acc,
                                       int r0, int tcb, int l15, float sgn)
{
#pragma unroll
    for (int c = 0; c < 4; ++c) {
        ushort4 p;
        p.x = f2bf(sgn * acc[c][0]); p.y = f2bf(sgn * acc[c][1]);
        p.z = f2bf(sgn * acc[c][2]); p.w = f2bf(sgn * acc[c][3]);
        *reinterpret_cast<ushort4*>(&C[foidx(r0, (tcb + c) * 16 + l15)]) = p;
    }
}

// ---------------------------------------------------------------------------
// Setup (1 block, 1024 threads = 16 waves, MFMA, 15 matmuls + 4 matvecs):
//   S = sigma+eps split bf16 hi(B0)/lo(stashed in regs)
//   lambda_max estimate: 3 power iterations + Rayleigh quotient (on S_hi)
//   NS: X <- 2X - X^T(S_hi X), X0 = I/(1.10*lambda), 4 iters, 2 barriers/iter
//   refinement (split S): T = S X, E = 2I - T (regs), W = X^T E
//   wsB = W_hi (global, from regs); M = I - W -> B2,B3 (f32 traces 1,2)
//   series P_j = M^j, j=2..4: orders 3..8 via Frobenius dots (old P in regs)
//   wsScal[0] = 0.5*(D*log(2pi) + logdet)
// ---------------------------------------------------------------------------
__global__ __launch_bounds__(1024) void gm_setup(
    const float* __restrict__ sigma, const float* __restrict__ eps,
    unsigned short* __restrict__ wsB, float* __restrict__ wsScal)
{
    __shared__ __align__(16) unsigned short B0[16384];  // S_hi
    __shared__ __align__(16) unsigned short B1[16384];  // X ping-pong / E_lo
    __shared__ __align__(16) unsigned short B2[16384];  // X ping-pong / M
    __shared__ __align__(16) unsigned short B3[16384];  // -T / E_hi / P_j
    __shared__ float sv[DIM];            // power-iter vector / tsum partials
    __shared__ float sy[DIM];            // power-iter matvec result
    __shared__ float sscal[1];

    const int tid  = threadIdx.x;
    const int lane = tid & 63;
    const int w    = tid >> 6;
    const int l15  = lane & 15;
    const int l4   = lane >> 4;
    const int tr   = w >> 1;          // output tile-row 0..7
    const int tcb  = (w & 1) * 4;     // output tile-col base 0 or 4
    const int r0   = tr * 16 + l4 * 4;

    // ---- load S = sigma + eps; hi -> B0, lo -> stashed registers ----
    ushort4 slo_st[4];                // S_lo for this thread's 2 vectors (32B)
#pragma unroll
    for (int h = 0; h < 2; ++h) {
        const int v = tid + h * 1024;          // vector index 0..2047
        const int c = v & 127, rb = v >> 7;    // rows rb*8..rb*8+7, column c
        ushort4 h0, h1, l0, l1;
#pragma unroll
        for (int j = 0; j < 8; ++j) {
            const int gi = (rb * 8 + j) * DIM + c;
            const float s = sigma[gi] + eps[gi];
            const unsigned short hi = f2bf(s);
            const unsigned short lo = f2bf(s - bfu(hi));
            if (j < 4) { ((unsigned short*)&h0)[j] = hi; ((unsigned short*)&l0)[j] = lo; }
            else       { ((unsigned short*)&h1)[j-4] = hi; ((unsigned short*)&l1)[j-4] = lo; }
        }
        const int f = v * 8;
        *reinterpret_cast<ushort4*>(&B0[f])     = h0;
        *reinterpret_cast<ushort4*>(&B0[f + 4]) = h1;
        slo_st[h * 2]     = l0;
        slo_st[h * 2 + 1] = l1;
    }
    if (tid < DIM) sv[tid] = 1.0f;    // power-iter v0
    __syncthreads();

    // ---- lambda_max: 3 power iterations + Rayleigh (thread = row) ----
    for (int pit = 0; pit < 3; ++pit) {
        if (tid < DIM) {
            const int base = ((tid >> 3) << 10) + (tid & 7);
            float y = 0.f;
            for (int c = 0; c < DIM; ++c) y += bfu(B0[base + (c << 3)]) * sv[c];
            sy[tid] = y;
        }
        __syncthreads();
        if (tid < 64) {
            float s = sy[tid] * sy[tid] + sy[tid + 64] * sy[tid + 64];
#pragma unroll
            for (int off = 32; off; off >>= 1) s += __shfl_xor(s, off, 64);
            if (tid == 0) sscal[0] = rsqrtf(s);
        }
        __syncthreads();
        if (tid < DIM) sv[tid] = sy[tid] * sscal[0];
        __syncthreads();
    }
    if (tid < DIM) {                  // Rayleigh: lambda = v^T S v (v normalized)
        const int base = ((tid >> 3) << 10) + (tid & 7);
        float y = 0.f;
        for (int c = 0; c < DIM; ++c) y += bfu(B0[base + (c << 3)]) * sv[c];
        sy[tid] = y * sv[tid];
    }
    __syncthreads();
    if (tid < 64) {
        float s = sy[tid] + sy[tid + 64];
#pragma unroll
        for (int off = 32; off; off >>= 1) s += __shfl_xor(s, off, 64);
        if (tid == 0) sscal[0] = 1.0f / (s * 1.10f);   // x0 = 1/(1.1*lambda_max)
    }
    __syncthreads();
    const unsigned short x0b = f2bf(sscal[0]);

    // ---- X0 = x0 * I -> B2 ----
#pragma unroll
    for (int h = 0; h < 2; ++h) {
        const int v = tid + h * 1024;
        const int c = v & 127, rb = v >> 7;
        ushort4 z0 = {0, 0, 0, 0}, z1 = {0, 0, 0, 0};
        const int dj = c - rb * 8;
        if (dj >= 0 && dj < 4) ((unsigned short*)&z0)[dj] = x0b;
        if (dj >= 4 && dj < 8) ((unsigned short*)&z1)[dj - 4] = x0b;
        const int f = v * 8;
        *reinterpret_cast<ushort4*>(&B2[f])     = z0;
        *reinterpret_cast<ushort4*>(&B2[f + 4]) = z1;
    }
    __syncthreads();

    // ---- Newton-Schulz, ping-pong B2<->B1, 2 barriers/iter ----
    for (int it = 0; it < NS_ITERS; ++it) {
        unsigned short* Xc = (it & 1) ? B1 : B2;
        unsigned short* Xo = (it & 1) ? B2 : B1;
        f32x4 acc[4];
#pragma unroll
        for (int c = 0; c < 4; ++c) { acc[c][0] = 0.f; acc[c][1] = 0.f; acc[c][2] = 0.f; acc[c][3] = 0.f; }
        mm_acc(B0, Xc, acc, tr, tcb, l15, l4);      // T = S X
        wb_vec(B3, acc, r0, tcb, l15, -1.0f);       // B3 = -T (no live readers)
        __syncthreads();
        f32x4 a2[4];
#pragma unroll
        for (int c = 0; c < 4; ++c) {
            const ushort4 x4 = *reinterpret_cast<const ushort4*>(&Xc[foidx(r0, (tcb + c) * 16 + l15)]);
            a2[c][0] = 2.0f * bfu(x4.x); a2[c][1] = 2.0f * bfu(x4.y);
            a2[c][2] = 2.0f * bfu(x4.z); a2[c][3] = 2.0f * bfu(x4.w);
        }
        mm_acc(Xc, B3, a2, tr, tcb, l15, l4);       // a2 = 2X - X^T T
        wb_vec(Xo, a2, r0, tcb, l15, 1.0f);         // Xo unread -> safe pre-barrier
        __syncthreads();
    }
    // X final in B2 (NS_ITERS even)

    // ---- restore S_lo -> B1 from stashed regs ----
#pragma unroll
    for (int h = 0; h < 2; ++h) {
        const int f = (tid + h * 1024) * 8;
        *reinterpret_cast<ushort4*>(&B1[f])     = slo_st[h * 2];
        *reinterpret_cast<ushort4*>(&B1[f + 4]) = slo_st[h * 2 + 1];
    }
    __syncthreads();

    // ---- refinement: T = (S_hi+S_lo) X; E = 2I - T (regs, split) ----
    ushort4 elv[4];
    {
        f32x4 acc[4];
#pragma unroll
        for (int c = 0; c < 4; ++c) { acc[c][0] = 0.f; acc[c][1] = 0.f; acc[c][2] = 0.f; acc[c][3] = 0.f; }
        mm_acc(B0, B2, acc, tr, tcb, l15, l4);
        mm_acc(B1, B2, acc, tr, tcb, l15, l4);
#pragma unroll
        for (int c = 0; c < 4; ++c) {
            const int col = (tcb + c) * 16 + l15;
            ushort4 eh;
#pragma unroll
            for (int j = 0; j < 4; ++j) {
                const float e = ((r0 + j == col) ? 2.0f : 0.0f) - acc[c][j];
                const unsigned short hi = f2bf(e);
                ((unsigned short*)&eh)[j] = hi;
                ((unsigned short*)&elv[c])[j] = f2bf(e - bfu(hi));
            }
            *reinterpret_cast<ushort4*>(&B3[foidx(r0, col)]) = eh;  // B3 unread now
        }
        __syncthreads();                            // B1 mm-reads done, E_hi ready
    }
#pragma unroll
    for (int c = 0; c < 4; ++c)
        *reinterpret_cast<ushort4*>(&B1[foidx(r0, (tcb + c) * 16 + l15)]) = elv[c];
    __syncthreads();                                // E_lo ready

    // ---- W = X^T E (split); write W_hi->global; M = I - W -> B2,B3 ----
    float tsum = 0.0f;
    ushort4 pold[4];
    {
        f32x4 acc[4];
#pragma unroll
        for (int c = 0; c < 4; ++c) { acc[c][0] = 0.f; acc[c][1] = 0.f; acc[c][2] = 0.f; acc[c][3] = 0.f; }
        mm_acc(B2, B3, acc, tr, tcb, l15, l4);      // X^T E_hi
        mm_acc(B2, B1, acc, tr, tcb, l15, l4);      // X^T E_lo
        __syncthreads();                            // B2/B3 reads done
#pragma unroll
        for (int c = 0; c < 4; ++c) {
            const int col = (tcb + c) * 16 + l15;
            const int f = foidx(r0, col);
            ushort4 wh, mv;
#pragma unroll
            for (int j = 0; j < 4; ++j) {
                const float wv = acc[c][j];
                ((unsigned short*)&wh)[j] = f2bf(wv);
                const float mf = ((r0 + j == col) ? 1.0f : 0.0f) - wv;  // f32 M
                ((unsigned short*)&mv)[j] = f2bf(mf);
                tsum += 0.5f * mf * mf + ((r0 + j == col) ? mf : 0.0f); // tr(M)+tr(M^2)/2
            }
            *reinterpret_cast<ushort4*>(&wsB[f]) = wh;   // global W_hi
            *reinterpret_cast<ushort4*>(&B2[f]) = mv;
            *reinterpret_cast<ushort4*>(&B3[f]) = mv;
            pold[c] = mv;
        }
        __syncthreads();
    }

    // ---- series: P_j = M^j, j=2..4; orders 2j-1, 2j via Frobenius dots ----
    for (int j = 2; j <= 4; ++j) {
        const float codd = 1.0f / (float)(2 * j - 1);
        const float cevn = 1.0f / (float)(2 * j);
        f32x4 acc[4];
#pragma unroll
        for (int c = 0; c < 4; ++c) { acc[c][0] = 0.f; acc[c][1] = 0.f; acc[c][2] = 0.f; acc[c][3] = 0.f; }
        mm_acc(B2, B3, acc, tr, tcb, l15, l4);      // M^T P_{j-1}
        __syncthreads();                            // B3 reads done
#pragma unroll
        for (int c = 0; c < 4; ++c) {
            const int f = foidx(r0, (tcb + c) * 16 + l15);
            ushort4 nw;
#pragma unroll
            for (int j4 = 0; j4 < 4; ++j4) {
                const float x = acc[c][j4];
                ((unsigned short*)&nw)[j4] = f2bf(x);
                tsum += x * bfu(((const unsigned short*)&pold[c])[j4]) * codd + x * x * cevn;
            }
            *reinterpret_cast<ushort4*>(&B3[f]) = nw;
            pold[c] = nw;
        }
        __syncthreads();
    }

    // ---- reduce tsum over 1024 threads ----
    {
        float s = tsum;
#pragma unroll
        for (int off = 1; off < 64; off <<= 1) s += __shfl_xor(s, off, 64);
        if (lane == 0) sv[w] = s;
    }
    __syncthreads();
    if (tid == 0) {
        float tot = 0.f;
        for (int i = 0; i < 16; ++i) tot += sv[i];
        wsScal[0] = 0.5f * ((float)DIM * LOG_2PI + tot);
    }
}

// ---------------------------------------------------------------------------
// Main kernel: persistent blocks, 64-row tiles (dot-form). UNCHANGED.
//   Y = (X_tile - mu)_bf16 @ W ;  quad[n] = sum_e Y[n][e]*diff[n][e]
//   out = 0.5*quad + log_den
// ---------------------------------------------------------------------------
__global__ __launch_bounds__(256) void gm_main(
    const float* __restrict__ X, const float* __restrict__ mu,
    const __hip_bfloat16* __restrict__ wsB, const float* __restrict__ wsScal,
    float* __restrict__ out, int ntiles)
{
    __shared__ __hip_bfloat16 sB[16 * 1024];  // 32KB, fragment-ordered W
    __shared__ unsigned short sA[64 * 128];   // 16KB, swizzled bf16 diff tile
    __shared__ float s_mu[DIM];

    const int tid  = threadIdx.x;
    const int lane = tid & 63;
    const int wave = tid >> 6;
    const int l15  = lane & 15;
    const int l4   = lane >> 4;

    {   // stage W (tile-invariant) and mu once
        const float4* bg = reinterpret_cast<const float4*>(wsB);
        float4* bs = reinterpret_cast<float4*>(sB);
#pragma unroll
        for (int i = 0; i < 8; ++i) bs[tid + i * 256] = bg[tid + i * 256];
        if (tid < DIM) s_mu[tid] = mu[tid];
    }
    const float logden = wsScal[0];
    __syncthreads();

    for (int t = blockIdx.x; t < ntiles; t += gridDim.x) {
        // ---- stage 64x128 diff tile -> bf16, XOR-swizzled ----
        const float4* xg = reinterpret_cast<const float4*>(X + (size_t)t * (64 * DIM));
#pragma unroll
        for (int i = 0; i < 8; ++i) {
            const int idx = tid + i * 256;
            const int r  = idx >> 5;
            const int c4 = idx & 31;
            float4 v = xg[idx];
            v.x -= s_mu[c4 * 4 + 0];
            v.y -= s_mu[c4 * 4 + 1];
            v.z -= s_mu[c4 * 4 + 2];
            v.w -= s_mu[c4 * 4 + 3];
            ushort4 b;
            b.x = f2bf(v.x); b.y = f2bf(v.y); b.z = f2bf(v.z); b.w = f2bf(v.w);
            char* p = (char*)sA + r * 256 + ((((c4 >> 1) ^ (r & 7)) << 4) | ((c4 & 1) << 3));
            *reinterpret_cast<ushort4*>(p) = b;
        }
        __syncthreads();

        // ---- MFMA: Y = diff @ W ----
        f32x4 acc[8];
#pragma unroll
        for (int c = 0; c < 8; ++c) { acc[c][0] = 0.f; acc[c][1] = 0.f; acc[c][2] = 0.f; acc[c][3] = 0.f; }

        const int arow = wave * 16 + l15;
        const char* aBase = (const char*)sA + arow * 256;
#pragma unroll
        for (int kk = 0; kk < 4; ++kk) {
            const int kchunk = kk * 4 + l4;
            bf16x8 af = *reinterpret_cast<const bf16x8*>(aBase + ((kchunk ^ (arow & 7)) << 4));
            const __hip_bfloat16* bbase = sB + kchunk * 1024 + l15 * 8;
#pragma unroll
            for (int c = 0; c < 8; ++c) {
                bf16x8 bf = *reinterpret_cast<const bf16x8*>(bbase + c * 128);
                acc[c] = __builtin_amdgcn_mfma_f32_16x16x32_bf16(af, bf, acc[c], 0, 0, 0);
            }
        }

        // ---- quad = rowdot(Y, diff): re-read own diff slices from sA ----
        float q0 = 0.f, q1 = 0.f, q2 = 0.f, q3 = 0.f;
#pragma unroll
        for (int c = 0; c < 8; ++c) {
            const int d = c * 16 + l15;
#pragma unroll
            for (int j = 0; j < 4; ++j) {
                const int r = wave * 16 + l4 * 4 + j;
                const int byt = r * 256 +
                    ((((d >> 3) ^ (r & 7)) << 4) | (((d >> 2) & 1) << 3) | ((d & 3) << 1));
                const unsigned short u = *reinterpret_cast<const unsigned short*>((const char*)sA + byt);
                const float df = __uint_as_float((unsigned int)u << 16);
                if (j == 0) q0 += acc[c][0] * df;
                else if (j == 1) q1 += acc[c][1] * df;
                else if (j == 2) q2 += acc[c][2] * df;
                else q3 += acc[c][3] * df;
            }
        }
#pragma unroll
        for (int off = 1; off < 16; off <<= 1) {
            q0 += __shfl_xor(q0, off, 64);
            q1 += __shfl_xor(q1, off, 64);
            q2 += __shfl_xor(q2, off, 64);
            q3 += __shfl_xor(q3, off, 64);
        }
        if (l15 == 0) {
            float4 o;
            o.x = 0.5f * q0 + logden;
            o.y = 0.5f * q1 + logden;
            o.z = 0.5f * q2 + logden;
            o.w = 0.5f * q3 + logden;
            *reinterpret_cast<float4*>(out + (size_t)t * 64 + wave * 16 + l4 * 4) = o;
        }
        __syncthreads();
    }
}

extern "C" void kernel_launch(void* const* d_in, const int* in_sizes, int n_in,
                              void* d_out, int out_size, void* d_ws, size_t ws_size,
                              hipStream_t stream) {
    const float* X     = (const float*)d_in[0];
    const float* mu    = (const float*)d_in[1];
    const float* sigma = (const float*)d_in[2];
    const float* eps   = (const float*)d_in[3];
    float* out = (float*)d_out;

    unsigned short* wsB = (unsigned short*)d_ws;
    float* wsScal = (float*)((char*)d_ws + 32768);

    const int N = in_sizes[0] / DIM;
    const int ntiles = N / 64;

    hipLaunchKernelGGL(gm_setup, dim3(1), dim3(1024), 0, stream, sigma, eps, wsB, wsScal);

    const int grid = ntiles < 768 ? ntiles : 768;
    hipLaunchKernelGGL(gm_main, dim3(grid), dim3(256), 0, stream,
                       X, mu, (const __hip_bfloat16*)wsB, wsScal, out, ntiles);
}

// Round 10
// 133.448 us; speedup vs baseline: 1.0123x; 1.0123x over previous
//
#include <hip/hip_runtime.h>
#include <hip/hip_bf16.h>

typedef __bf16 bf16x8 __attribute__((ext_vector_type(8)));
typedef float f32x4 __attribute__((ext_vector_type(4)));

#define DIM 128
#define LOG_2PI 1.8378770664093453f
#define NS_ITERS 4   // even (X ends in B2); e0^(2^4) squared by refinement < bf16 floor

__device__ __forceinline__ unsigned short f2bf(float f) {
    unsigned int u = __float_as_uint(f);
    u += 0x7FFFu + ((u >> 16) & 1u);
    return (unsigned short)(u >> 16);
}
__device__ __forceinline__ float bfu(unsigned short u) {
    return __uint_as_float((unsigned int)u << 16);
}
// fragment-order index: FO[(r>>3)*1024 + c*8 + (r&7)] = M[r][c]
__device__ __forceinline__ int foidx(int r, int c) {
    return ((r >> 3) << 10) + (c << 3) + (r & 7);
}

// 8-wave matmul: wave (wr,wc) owns 2 row-tiles x 4 col-tiles.
// acc[rt][c] += (P^T Q) tile(wr*2+rt, wc*4+c). 6 LDS reads per kk for 8 MFMAs.
__device__ __forceinline__ void mm_acc8(const unsigned short* __restrict__ Ps,
                                        const unsigned short* __restrict__ Qs,
                                        f32x4 acc[2][4], int wr, int tcb, int l15, int l4)
{
#pragma unroll
    for (int kk = 0; kk < 4; ++kk) {
        const int kc = kk * 4 + l4;
        const bf16x8 a0 = *reinterpret_cast<const bf16x8*>(Ps + (kc << 10) + ((wr * 32 + l15) << 3));
        const bf16x8 a1 = *reinterpret_cast<const bf16x8*>(Ps + (kc << 10) + ((wr * 32 + 16 + l15) << 3));
#pragma unroll
        for (int c = 0; c < 4; ++c) {
            const bf16x8 b = *reinterpret_cast<const bf16x8*>(Qs + (kc << 10) + (((tcb + c) * 16 + l15) << 3));
            acc[0][c] = __builtin_amdgcn_mfma_f32_16x16x32_bf16(a0, b, acc[0][c], 0, 0, 0);
            acc[1][c] = __builtin_amdgcn_mfma_f32_16x16x32_bf16(a1, b, acc[1][c], 0, 0, 0);
        }
    }
}

__device__ __forceinline__ void zacc(f32x4 acc[2][4]) {
#pragma unroll
    for (int rt = 0; rt < 2; ++rt)
#pragma unroll
        for (int c = 0; c < 4; ++c) { acc[rt][c][0] = 0.f; acc[rt][c][1] = 0.f; acc[rt][c][2] = 0.f; acc[rt][c][3] = 0.f; }
}

// packed writeback (b64 per tile-column)
__device__ __forceinline__ void wb8(unsigned short* __restrict__ C, f32x4 acc[2][4],
                                    int wr, int tcb, int l15, int l4, float sgn)
{
#pragma unroll
    for (int rt = 0; rt < 2; ++rt) {
        const int r0 = wr * 32 + rt * 16 + l4 * 4;
#pragma unroll
        for (int c = 0; c < 4; ++c) {
            ushort4 p;
            p.x = f2bf(sgn * acc[rt][c][0]); p.y = f2bf(sgn * acc[rt][c][1]);
            p.z = f2bf(sgn * acc[rt][c][2]); p.w = f2bf(sgn * acc[rt][c][3]);
            *reinterpret_cast<ushort4*>(&C[foidx(r0, (tcb + c) * 16 + l15)]) = p;
        }
    }
}

// ---------------------------------------------------------------------------
// Setup (1 block, 512 threads = 8 waves, MFMA, 15 matmuls):
//   S = sigma+eps split bf16 hi(B0)/lo(stashed in regs)
//   lambda est: v = normalize(S*1); rho = v^T S v; lam = min(gersh, 1.10*rho)
//   NS: X <- 2X - X^T(S_hi X), X0 = I/lam, 4 iters, 2 barriers/iter
//   refinement (split S): T = S X, E = 2I - T (regs), W = X^T E
//   wsB = W_hi (global); M = I - W -> B2,B3 (f32 traces 1,2)
//   series P_j = M^j, j=2..4: orders 3..8 via Frobenius dots (old P in regs)
//   wsScal[0] = 0.5*(D*log(2pi) + logdet)
// ---------------------------------------------------------------------------
__global__ __launch_bounds__(512) void gm_setup(
    const float* __restrict__ sigma, const float* __restrict__ eps,
    unsigned short* __restrict__ wsB, float* __restrict__ wsScal)
{
    __shared__ __align__(16) unsigned short B0[16384];  // S_hi
    __shared__ __align__(16) unsigned short B1[16384];  // X ping-pong / E_lo
    __shared__ __align__(16) unsigned short B2[16384];  // X ping-pong / M
    __shared__ __align__(16) unsigned short B3[16384];  // -T / E_hi / P_j
    __shared__ float sv[DIM];            // row-sum vec -> rayleigh vec / tsum partials
    __shared__ float sy[DIM];            // abs row sums -> matvec result
    __shared__ float sscal[2];

    const int tid  = threadIdx.x;
    const int lane = tid & 63;
    const int w    = tid >> 6;        // 0..7
    const int l15  = lane & 15;
    const int l4   = lane >> 4;
    const int wr   = w >> 1;          // row-tile pair 0..3 (rows wr*32..wr*32+31)
    const int tcb  = (w & 1) * 4;     // col-tile base 0 or 4

    // ---- load S = sigma + eps; hi -> B0, lo -> stashed registers ----
    ushort4 slo_st[8];                // S_lo for this thread's 4 vectors (64B)
#pragma unroll
    for (int h = 0; h < 4; ++h) {
        const int v = tid + h * 512;           // vector index 0..2047
        const int c = v & 127, rb = v >> 7;    // rows rb*8..rb*8+7, column c
        ushort4 h0, h1, l0, l1;
#pragma unroll
        for (int j = 0; j < 8; ++j) {
            const int gi = (rb * 8 + j) * DIM + c;
            const float s = sigma[gi] + eps[gi];
            const unsigned short hi = f2bf(s);
            const unsigned short lo = f2bf(s - bfu(hi));
            if (j < 4) { ((unsigned short*)&h0)[j] = hi; ((unsigned short*)&l0)[j] = lo; }
            else       { ((unsigned short*)&h1)[j-4] = hi; ((unsigned short*)&l1)[j-4] = lo; }
        }
        const int f = v * 8;
        *reinterpret_cast<ushort4*>(&B0[f])     = h0;
        *reinterpret_cast<ushort4*>(&B0[f + 4]) = h1;
        slo_st[h * 2]     = l0;
        slo_st[h * 2 + 1] = l1;
    }
    __syncthreads();

    // ---- row sums (signed + abs) in one pass: y = S*1, g = gersh row sums ----
    if (tid < DIM) {
        const int base = ((tid >> 3) << 10) + (tid & 7);
        float ss = 0.f, sa = 0.f;
        for (int c = 0; c < DIM; ++c) {
            const float x = bfu(B0[base + (c << 3)]);
            ss += x; sa += fabsf(x);
        }
        sv[tid] = ss; sy[tid] = sa;
    }
    __syncthreads();
    if (tid < 64) {
        float n = sv[tid] * sv[tid] + sv[tid + 64] * sv[tid + 64];
        float g = fmaxf(sy[tid], sy[tid + 64]);
#pragma unroll
        for (int off = 32; off; off >>= 1) {
            n += __shfl_xor(n, off, 64);
            g = fmaxf(g, __shfl_xor(g, off, 64));
        }
        if (tid == 0) { sscal[0] = rsqrtf(n); sscal[1] = g; }
    }
    __syncthreads();
    if (tid < DIM) sv[tid] *= sscal[0];   // v normalized
    __syncthreads();
    if (tid < DIM) {                      // z = S v; rayleigh partial z*v
        const int base = ((tid >> 3) << 10) + (tid & 7);
        float z = 0.f;
        for (int c = 0; c < DIM; ++c) z += bfu(B0[base + (c << 3)]) * sv[c];
        sy[tid] = z * sv[tid];
    }
    __syncthreads();
    if (tid < 64) {
        float s = sy[tid] + sy[tid + 64];
#pragma unroll
        for (int off = 32; off; off >>= 1) s += __shfl_xor(s, off, 64);
        if (tid == 0) {
            const float lam = fminf(sscal[1], 1.10f * s);
            sscal[0] = 1.0f / lam;        // x0
        }
    }
    __syncthreads();
    const unsigned short x0b = f2bf(sscal[0]);

    // ---- X0 = x0 * I -> B2 ----
#pragma unroll
    for (int h = 0; h < 4; ++h) {
        const int v = tid + h * 512;
        const int c = v & 127, rb = v >> 7;
        ushort4 z0 = {0, 0, 0, 0}, z1 = {0, 0, 0, 0};
        const int dj = c - rb * 8;
        if (dj >= 0 && dj < 4) ((unsigned short*)&z0)[dj] = x0b;
        if (dj >= 4 && dj < 8) ((unsigned short*)&z1)[dj - 4] = x0b;
        const int f = v * 8;
        *reinterpret_cast<ushort4*>(&B2[f])     = z0;
        *reinterpret_cast<ushort4*>(&B2[f + 4]) = z1;
    }
    __syncthreads();

    // ---- Newton-Schulz, ping-pong B2<->B1, 2 barriers/iter ----
    for (int it = 0; it < NS_ITERS; ++it) {
        unsigned short* Xc = (it & 1) ? B1 : B2;
        unsigned short* Xo = (it & 1) ? B2 : B1;
        f32x4 acc[2][4];
        zacc(acc);
        mm_acc8(B0, Xc, acc, wr, tcb, l15, l4);     // T = S X
        wb8(B3, acc, wr, tcb, l15, l4, -1.0f);      // B3 = -T (no live readers)
        __syncthreads();
        f32x4 a2[2][4];
#pragma unroll
        for (int rt = 0; rt < 2; ++rt) {
            const int r0 = wr * 32 + rt * 16 + l4 * 4;
#pragma unroll
            for (int c = 0; c < 4; ++c) {
                const ushort4 x4 = *reinterpret_cast<const ushort4*>(&Xc[foidx(r0, (tcb + c) * 16 + l15)]);
                a2[rt][c][0] = 2.0f * bfu(x4.x); a2[rt][c][1] = 2.0f * bfu(x4.y);
                a2[rt][c][2] = 2.0f * bfu(x4.z); a2[rt][c][3] = 2.0f * bfu(x4.w);
            }
        }
        mm_acc8(Xc, B3, a2, wr, tcb, l15, l4);      // a2 = 2X - X^T T
        wb8(Xo, a2, wr, tcb, l15, l4, 1.0f);        // Xo unread -> safe pre-barrier
        __syncthreads();
    }
    // X final in B2 (NS_ITERS even)

    // ---- restore S_lo -> B1 from stashed regs ----
#pragma unroll
    for (int h = 0; h < 4; ++h) {
        const int f = (tid + h * 512) * 8;
        *reinterpret_cast<ushort4*>(&B1[f])     = slo_st[h * 2];
        *reinterpret_cast<ushort4*>(&B1[f + 4]) = slo_st[h * 2 + 1];
    }
    __syncthreads();

    // ---- refinement: T = (S_hi+S_lo) X; E = 2I - T (regs, split) ----
    ushort4 elv[2][4];
    {
        f32x4 acc[2][4];
        zacc(acc);
        mm_acc8(B0, B2, acc, wr, tcb, l15, l4);
        mm_acc8(B1, B2, acc, wr, tcb, l15, l4);
#pragma unroll
        for (int rt = 0; rt < 2; ++rt) {
            const int r0 = wr * 32 + rt * 16 + l4 * 4;
#pragma unroll
            for (int c = 0; c < 4; ++c) {
                const int col = (tcb + c) * 16 + l15;
                ushort4 eh;
#pragma unroll
                for (int j = 0; j < 4; ++j) {
                    const float e = ((r0 + j == col) ? 2.0f : 0.0f) - acc[rt][c][j];
                    const unsigned short hi = f2bf(e);
                    ((unsigned short*)&eh)[j] = hi;
                    ((unsigned short*)&elv[rt][c])[j] = f2bf(e - bfu(hi));
                }
                *reinterpret_cast<ushort4*>(&B3[foidx(r0, col)]) = eh;  // B3 unread now
            }
        }
        __syncthreads();                            // B1 mm-reads done, E_hi ready
    }
#pragma unroll
    for (int rt = 0; rt < 2; ++rt) {
        const int r0 = wr * 32 + rt * 16 + l4 * 4;
#pragma unroll
        for (int c = 0; c < 4; ++c)
            *reinterpret_cast<ushort4*>(&B1[foidx(r0, (tcb + c) * 16 + l15)]) = elv[rt][c];
    }
    __syncthreads();                                // E_lo ready

    // ---- W = X^T E (split); write W_hi->global; M = I - W -> B2,B3 ----
    float tsum = 0.0f;
    ushort4 pold[2][4];
    {
        f32x4 acc[2][4];
        zacc(acc);
        mm_acc8(B2, B3, acc, wr, tcb, l15, l4);     // X^T E_hi
        mm_acc8(B2, B1, acc, wr, tcb, l15, l4);     // X^T E_lo
        __syncthreads();                            // B2/B3 reads done
#pragma unroll
        for (int rt = 0; rt < 2; ++rt) {
            const int r0 = wr * 32 + rt * 16 + l4 * 4;
#pragma unroll
            for (int c = 0; c < 4; ++c) {
                const int col = (tcb + c) * 16 + l15;
                const int f = foidx(r0, col);
                ushort4 wh, mv;
#pragma unroll
                for (int j = 0; j < 4; ++j) {
                    const float wv = acc[rt][c][j];
                    ((unsigned short*)&wh)[j] = f2bf(wv);
                    const float mf = ((r0 + j == col) ? 1.0f : 0.0f) - wv;  // f32 M
                    ((unsigned short*)&mv)[j] = f2bf(mf);
                    tsum += 0.5f * mf * mf + ((r0 + j == col) ? mf : 0.0f); // tr(M)+tr(M^2)/2
                }
                *reinterpret_cast<ushort4*>(&wsB[f]) = wh;   // global W_hi
                *reinterpret_cast<ushort4*>(&B2[f]) = mv;
                *reinterpret_cast<ushort4*>(&B3[f]) = mv;
                pold[rt][c] = mv;
            }
        }
        __syncthreads();
    }

    // ---- series: P_j = M^j, j=2..4; orders 2j-1, 2j via Frobenius dots ----
    for (int j = 2; j <= 4; ++j) {
        const float codd = 1.0f / (float)(2 * j - 1);
        const float cevn = 1.0f / (float)(2 * j);
        f32x4 acc[2][4];
        zacc(acc);
        mm_acc8(B2, B3, acc, wr, tcb, l15, l4);     // M^T P_{j-1}
        __syncthreads();                            // B3 reads done
#pragma unroll
        for (int rt = 0; rt < 2; ++rt) {
            const int r0 = wr * 32 + rt * 16 + l4 * 4;
#pragma unroll
            for (int c = 0; c < 4; ++c) {
                const int f = foidx(r0, (tcb + c) * 16 + l15);
                ushort4 nw;
#pragma unroll
                for (int j4 = 0; j4 < 4; ++j4) {
                    const float x = acc[rt][c][j4];
                    ((unsigned short*)&nw)[j4] = f2bf(x);
                    tsum += x * bfu(((const unsigned short*)&pold[rt][c])[j4]) * codd + x * x * cevn;
                }
                *reinterpret_cast<ushort4*>(&B3[f]) = nw;
                pold[rt][c] = nw;
            }
        }
        __syncthreads();
    }

    // ---- reduce tsum over 512 threads ----
    {
        float s = tsum;
#pragma unroll
        for (int off = 1; off < 64; off <<= 1) s += __shfl_xor(s, off, 64);
        if (lane == 0) sv[w] = s;
    }
    __syncthreads();
    if (tid == 0) {
        float tot = 0.f;
        for (int i = 0; i < 8; ++i) tot += sv[i];
        wsScal[0] = 0.5f * ((float)DIM * LOG_2PI + tot);
    }
}

// ---------------------------------------------------------------------------
// Main kernel: persistent blocks, 64-row tiles (dot-form). UNCHANGED.
//   Y = (X_tile - mu)_bf16 @ W ;  quad[n] = sum_e Y[n][e]*diff[n][e]
//   out = 0.5*quad + log_den
// ---------------------------------------------------------------------------
__global__ __launch_bounds__(256) void gm_main(
    const float* __restrict__ X, const float* __restrict__ mu,
    const __hip_bfloat16* __restrict__ wsB, const float* __restrict__ wsScal,
    float* __restrict__ out, int ntiles)
{
    __shared__ __hip_bfloat16 sB[16 * 1024];  // 32KB, fragment-ordered W
    __shared__ unsigned short sA[64 * 128];   // 16KB, swizzled bf16 diff tile
    __shared__ float s_mu[DIM];

    const int tid  = threadIdx.x;
    const int lane = tid & 63;
    const int wave = tid >> 6;
    const int l15  = lane & 15;
    const int l4   = lane >> 4;

    {   // stage W (tile-invariant) and mu once
        const float4* bg = reinterpret_cast<const float4*>(wsB);
        float4* bs = reinterpret_cast<float4*>(sB);
#pragma unroll
        for (int i = 0; i < 8; ++i) bs[tid + i * 256] = bg[tid + i * 256];
        if (tid < DIM) s_mu[tid] = mu[tid];
    }
    const float logden = wsScal[0];
    __syncthreads();

    for (int t = blockIdx.x; t < ntiles; t += gridDim.x) {
        // ---- stage 64x128 diff tile -> bf16, XOR-swizzled ----
        const float4* xg = reinterpret_cast<const float4*>(X + (size_t)t * (64 * DIM));
#pragma unroll
        for (int i = 0; i < 8; ++i) {
            const int idx = tid + i * 256;
            const int r  = idx >> 5;
            const int c4 = idx & 31;
            float4 v = xg[idx];
            v.x -= s_mu[c4 * 4 + 0];
            v.y -= s_mu[c4 * 4 + 1];
            v.z -= s_mu[c4 * 4 + 2];
            v.w -= s_mu[c4 * 4 + 3];
            ushort4 b;
            b.x = f2bf(v.x); b.y = f2bf(v.y); b.z = f2bf(v.z); b.w = f2bf(v.w);
            char* p = (char*)sA + r * 256 + ((((c4 >> 1) ^ (r & 7)) << 4) | ((c4 & 1) << 3));
            *reinterpret_cast<ushort4*>(p) = b;
        }
        __syncthreads();

        // ---- MFMA: Y = diff @ W ----
        f32x4 acc[8];
#pragma unroll
        for (int c = 0; c < 8; ++c) { acc[c][0] = 0.f; acc[c][1] = 0.f; acc[c][2] = 0.f; acc[c][3] = 0.f; }

        const int arow = wave * 16 + l15;
        const char* aBase = (const char*)sA + arow * 256;
#pragma unroll
        for (int kk = 0; kk < 4; ++kk) {
            const int kchunk = kk * 4 + l4;
            bf16x8 af = *reinterpret_cast<const bf16x8*>(aBase + ((kchunk ^ (arow & 7)) << 4));
            const __hip_bfloat16* bbase = sB + kchunk * 1024 + l15 * 8;
#pragma unroll
            for (int c = 0; c < 8; ++c) {
                bf16x8 bf = *reinterpret_cast<const bf16x8*>(bbase + c * 128);
                acc[c] = __builtin_amdgcn_mfma_f32_16x16x32_bf16(af, bf, acc[c], 0, 0, 0);
            }
        }

        // ---- quad = rowdot(Y, diff): re-read own diff slices from sA ----
        float q0 = 0.f, q1 = 0.f, q2 = 0.f, q3 = 0.f;
#pragma unroll
        for (int c = 0; c < 8; ++c) {
            const int d = c * 16 + l15;
#pragma unroll
            for (int j = 0; j < 4; ++j) {
                const int r = wave * 16 + l4 * 4 + j;
                const int byt = r * 256 +
                    ((((d >> 3) ^ (r & 7)) << 4) | (((d >> 2) & 1) << 3) | ((d & 3) << 1));
                const unsigned short u = *reinterpret_cast<const unsigned short*>((const char*)sA + byt);
                const float df = __uint_as_float((unsigned int)u << 16);
                if (j == 0) q0 += acc[c][0] * df;
                else if (j == 1) q1 += acc[c][1] * df;
                else if (j == 2) q2 += acc[c][2] * df;
                else q3 += acc[c][3] * df;
            }
        }
#pragma unroll
        for (int off = 1; off < 16; off <<= 1) {
            q0 += __shfl_xor(q0, off, 64);
            q1 += __shfl_xor(q1, off, 64);
            q2 += __shfl_xor(q2, off, 64);
            q3 += __shfl_xor(q3, off, 64);
        }
        if (l15 == 0) {
            float4 o;
            o.x = 0.5f * q0 + logden;
            o.y = 0.5f * q1 + logden;
            o.z = 0.5f * q2 + logden;
            o.w = 0.5f * q3 + logden;
            *reinterpret_cast<float4*>(out + (size_t)t * 64 + wave * 16 + l4 * 4) = o;
        }
        __syncthreads();
    }
}

extern "C" void kernel_launch(void* const* d_in, const int* in_sizes, int n_in,
                              void* d_out, int out_size, void* d_ws, size_t ws_size,
                              hipStream_t stream) {
    const float* X     = (const float*)d_in[0];
    const float* mu    = (const float*)d_in[1];
    const float* sigma = (const float*)d_in[2];
    const float* eps   = (const float*)d_in[3];
    float* out = (float*)d_out;

    unsigned short* wsB = (unsigned short*)d_ws;
    float* wsScal = (float*)((char*)d_ws + 32768);

    const int N = in_sizes[0] / DIM;
    const int ntiles = N / 64;

    hipLaunchKernelGGL(gm_setup, dim3(1), dim3(512), 0, stream, sigma, eps, wsB, wsScal);

    const int grid = ntiles < 768 ? ntiles : 768;
    hipLaunchKernelGGL(gm_main, dim3(grid), dim3(256), 0, stream,
                       X, mu, (const __hip_bfloat16*)wsB, wsScal, out, ntiles);
}